// Round 4
// baseline (12841.606 us; speedup 1.0000x reference)
//
#include <hip/hip_runtime.h>
#include <hip/hip_bf16.h>

#define HD 768
#define N_NODES 16383
#define NLEAF_OFF 8191     // first leaf node index (level d=13 offset)
#define NHF 12582144       // N_NODES * HD
#define TEMP 3.0f

using bf16 = __hip_bfloat16;

__device__ __forceinline__ float sigm(float x) { return 1.0f / (1.0f + __expf(-x)); }
__device__ __forceinline__ float b2f(bf16 v)   { return __bfloat162float(v); }
__device__ __forceinline__ bf16  f2b(float v)  { return __float2bfloat16(v); }

// ---------------------------------------------------------------------------
// Leaves, pass 1: hc = cc = 0 -> gather + activation. Writes bf16 h, c.
// ---------------------------------------------------------------------------
__global__ __launch_bounds__(256) void leaf1_k(
    const int* __restrict__ ids,
    const float* __restrict__ Wb, const float* __restrict__ bb,
    bf16* __restrict__ h_all, bf16* __restrict__ c_all)
{
    int idx = blockIdx.x * blockDim.x + threadIdx.x;
    if (idx >= 8192 * HD) return;
    int i = idx / HD, j = idx - i * HD;
    int g = NLEAF_OFF + i;
    int id = ids[g];
    const float* w = Wb + (size_t)id * 3 * HD;
    float iv = sigm(w[j] + bb[j]);
    float ov = sigm(w[HD + j] + bb[HD + j]);
    float gv = tanhf(w[2 * HD + j] + bb[2 * HD + j]);
    float c = iv * gv;
    h_all[(size_t)g * HD + j] = f2b(ov * tanhf(c));
    c_all[(size_t)g * HD + j] = f2b(c);
}

// ---------------------------------------------------------------------------
// Leaves, pass 2: h3 = o * tanh(i*g) from Wt row (cc = 0).
// ---------------------------------------------------------------------------
__global__ __launch_bounds__(256) void leaf2_k(
    const int* __restrict__ ids,
    const float* __restrict__ Wt, const float* __restrict__ bt,
    bf16* __restrict__ h3_all)
{
    int idx = blockIdx.x * blockDim.x + threadIdx.x;
    if (idx >= 8192 * HD) return;
    int i = idx / HD, j = idx - i * HD;
    int g = NLEAF_OFF + i;
    int id = ids[g];
    const float* w = Wt + (size_t)id * 3 * HD;
    float iv = sigm(w[j] + bt[j]);
    float ov = sigm(w[HD + j] + bt[HD + j]);
    float gv = tanhf(w[2 * HD + j] + bt[2 * HD + j]);
    float c = iv * gv;
    h3_all[(size_t)g * HD + j] = f2b(ov * tanhf(c));
}

// ---------------------------------------------------------------------------
// Pass-1 level kernel (fused GEMV + cell). One thread owns (parent i, col j).
// 4 parents per block (register-blocked), children rows staged in LDS.
// A row (len 1536) = [h(2g+1), h(2g+2)] contiguous in h_all.
// Ub_iou[l,h,o] at (l*768+h)*2304 + o ; Ub_f[kk,l,h,o] at ((kk*2+l)*768+h)*768 + o.
// ---------------------------------------------------------------------------
__global__ __launch_bounds__(256) void lvl1_k(
    const int* __restrict__ ids,
    bf16* __restrict__ h_all, bf16* __restrict__ c_all,
    const float* __restrict__ Ub_iou, const float* __restrict__ Ub_f,
    const float* __restrict__ Wb_iou, const float* __restrict__ bb_iou,
    const float* __restrict__ Wb_f, const float* __restrict__ bb_f,
    int n, int off)
{
    __shared__ float sA[4][1536];
    int tx = threadIdx.x;
    int j = blockIdx.x * 256 + tx;          // 0..767
    int base = blockIdx.y * 4;

    for (int p = 0; p < 4; ++p) {
        int i = base + p;
        bool ok = (i < n);
        size_t cb = ok ? (size_t)(2 * (off + i) + 1) * HD : 0;
        for (int k = tx; k < 1536; k += 256)
            sA[p][k] = ok ? b2f(h_all[cb + k]) : 0.f;
    }
    __syncthreads();

    float ai[4] = {}, ao[4] = {}, ag[4] = {}, af0[4] = {}, af1[4] = {};
    for (int k = 0; k < 1536; ++k) {
        const float* urow = Ub_iou + (size_t)k * 2304;
        float ui = urow[j];
        float uo = urow[HD + j];
        float ug = urow[2 * HD + j];
        int l = (k >= HD);
        int h = k - l * HD;
        float uf0 = Ub_f[(((size_t)(0 * 2 + l)) * HD + h) * HD + j];
        float uf1 = Ub_f[(((size_t)(1 * 2 + l)) * HD + h) * HD + j];
#pragma unroll
        for (int p = 0; p < 4; ++p) {
            float a = sA[p][k];
            ai[p]  = fmaf(a, ui,  ai[p]);
            ao[p]  = fmaf(a, uo,  ao[p]);
            ag[p]  = fmaf(a, ug,  ag[p]);
            af0[p] = fmaf(a, uf0, af0[p]);
            af1[p] = fmaf(a, uf1, af1[p]);
        }
    }

    for (int p = 0; p < 4; ++p) {
        int i = base + p;
        if (i >= n) break;
        int g = off + i;
        int id = ids[g];
        const float* w = Wb_iou + (size_t)id * 3 * HD;
        float iv = sigm(ai[p] + w[j] + bb_iou[j]);
        float ov = sigm(ao[p] + w[HD + j] + bb_iou[HD + j]);
        float gv = tanhf(ag[p] + w[2 * HD + j] + bb_iou[2 * HD + j]);
        float xf = Wb_f[(size_t)id * HD + j] + bb_f[j];
        float f0 = sigm(af0[p] + xf);
        float f1 = sigm(af1[p] + xf);
        float c = iv * gv
                + f0 * b2f(c_all[(size_t)(2 * g + 1) * HD + j])
                + f1 * b2f(c_all[(size_t)(2 * g + 2) * HD + j]);
        h_all[(size_t)g * HD + j] = f2b(ov * tanhf(c));
        c_all[(size_t)g * HD + j] = f2b(c);
    }
}

// ---------------------------------------------------------------------------
// Pass-2 kernel for ALL non-leaf nodes g in [0, 8191). A row (len 2304) =
// [h(g), h(2g+1), h(2g+2)]. Ut_iou[l,h,o] at (l*768+h)*2304+o (l=0 self);
// Ut_f[kk,l,h,o] at ((kk*3+l)*768+h)*768+o. cc = [c(g), c(2g+1), c(2g+2)].
// ---------------------------------------------------------------------------
__global__ __launch_bounds__(256) void lvl2_k(
    const int* __restrict__ ids,
    const bf16* __restrict__ h_all, const bf16* __restrict__ c_all,
    bf16* __restrict__ h3_all,
    const float* __restrict__ Ut_iou, const float* __restrict__ Ut_f,
    const float* __restrict__ Wt_iou, const float* __restrict__ bt_iou,
    const float* __restrict__ Wt_f, const float* __restrict__ bt_f)
{
    __shared__ float sA[4][2304];
    int tx = threadIdx.x;
    int j = blockIdx.x * 256 + tx;
    int base = blockIdx.y * 4;

    for (int p = 0; p < 4; ++p) {
        int g = base + p;
        bool ok = (g < NLEAF_OFF);
        size_t self = ok ? (size_t)g * HD : 0;
        size_t cb   = ok ? (size_t)(2 * g + 1) * HD : 0;
        for (int k = tx; k < 768; k += 256)
            sA[p][k] = ok ? b2f(h_all[self + k]) : 0.f;
        for (int k = 768 + tx; k < 2304; k += 256)
            sA[p][k] = ok ? b2f(h_all[cb + (k - 768)]) : 0.f;
    }
    __syncthreads();

    float ai[4] = {}, ao[4] = {}, ag[4] = {}, af0[4] = {}, af1[4] = {}, af2[4] = {};
    for (int k = 0; k < 2304; ++k) {
        const float* urow = Ut_iou + (size_t)k * 2304;
        float ui = urow[j];
        float uo = urow[HD + j];
        float ug = urow[2 * HD + j];
        int l = (k >= HD) + (k >= 2 * HD);
        int h = k - l * HD;
        float uf0 = Ut_f[(((size_t)(0 * 3 + l)) * HD + h) * HD + j];
        float uf1 = Ut_f[(((size_t)(1 * 3 + l)) * HD + h) * HD + j];
        float uf2 = Ut_f[(((size_t)(2 * 3 + l)) * HD + h) * HD + j];
#pragma unroll
        for (int p = 0; p < 4; ++p) {
            float a = sA[p][k];
            ai[p]  = fmaf(a, ui,  ai[p]);
            ao[p]  = fmaf(a, uo,  ao[p]);
            ag[p]  = fmaf(a, ug,  ag[p]);
            af0[p] = fmaf(a, uf0, af0[p]);
            af1[p] = fmaf(a, uf1, af1[p]);
            af2[p] = fmaf(a, uf2, af2[p]);
        }
    }

    for (int p = 0; p < 4; ++p) {
        int g = base + p;
        if (g >= NLEAF_OFF) break;
        int id = ids[g];
        const float* w = Wt_iou + (size_t)id * 3 * HD;
        float iv = sigm(ai[p] + w[j] + bt_iou[j]);
        float ov = sigm(ao[p] + w[HD + j] + bt_iou[HD + j]);
        float gv = tanhf(ag[p] + w[2 * HD + j] + bt_iou[2 * HD + j]);
        float xf = Wt_f[(size_t)id * HD + j] + bt_f[j];
        float f0 = sigm(af0[p] + xf);
        float f1 = sigm(af1[p] + xf);
        float f2 = sigm(af2[p] + xf);
        float c = iv * gv
                + f0 * b2f(c_all[(size_t)g * HD + j])
                + f1 * b2f(c_all[(size_t)(2 * g + 1) * HD + j])
                + f2 * b2f(c_all[(size_t)(2 * g + 2) * HD + j]);
        h3_all[(size_t)g * HD + j] = f2b(ov * tanhf(c));
    }
}

// ---------------------------------------------------------------------------
// Naive FFN layers. One thread per (node, j), 4 nodes/block, A rows in LDS.
// MODE 0: t1 = relu(h3 @ W1 + b1).  MODE 1: h4 = t1 @ W2 + b2.
// ---------------------------------------------------------------------------
template <int MODE>
__global__ __launch_bounds__(256) void ffn_k(
    const bf16* __restrict__ X, const float* __restrict__ W,
    const float* __restrict__ b, bf16* __restrict__ Y)
{
    __shared__ float sA[4][768];
    int tx = threadIdx.x;
    int j = blockIdx.x * 256 + tx;
    int base = blockIdx.y * 4;

    for (int p = 0; p < 4; ++p) {
        int g = base + p;
        bool ok = (g < N_NODES);
        size_t rb = ok ? (size_t)g * HD : 0;
        for (int k = tx; k < 768; k += 256)
            sA[p][k] = ok ? b2f(X[rb + k]) : 0.f;
    }
    __syncthreads();

    float acc[4] = {};
    for (int k = 0; k < 768; ++k) {
        float u = W[(size_t)k * HD + j];
#pragma unroll
        for (int p = 0; p < 4; ++p)
            acc[p] = fmaf(sA[p][k], u, acc[p]);
    }

    for (int p = 0; p < 4; ++p) {
        int g = base + p;
        if (g >= N_NODES) break;
        float v = acc[p] + b[j];
        if constexpr (MODE == 0) v = fmaxf(v, 0.f);
        Y[(size_t)g * HD + j] = f2b(v);
    }
}

// ---------------------------------------------------------------------------
// Heads: one 64-lane wave per node. Lane t computes ap column t; lanes 0-3
// also compute hl/il logits. Three softmaxes -> FP32 out row of 68.
// ---------------------------------------------------------------------------
__global__ __launch_bounds__(64) void heads_k(
    const bf16* __restrict__ h4, const int* __restrict__ mask,
    const float* __restrict__ hlW, const float* __restrict__ hlb,
    const float* __restrict__ intW, const float* __restrict__ intb,
    const float* __restrict__ actW, const float* __restrict__ actb,
    float* __restrict__ out)
{
    int g = blockIdx.x;
    int t = threadIdx.x;
    __shared__ float sh[HD];
    __shared__ float sm[4];

    for (int k = t; k < HD; k += 64)
        sh[k] = b2f(h4[(size_t)g * HD + k]);
    __syncthreads();

    if (t < 2) {
        float a = hlb[t];
        for (int k = 0; k < HD; ++k) a = fmaf(sh[k], hlW[k * 2 + t], a);
        sm[t] = a;
    } else if (t < 4) {
        int c = t - 2;
        float a = intb[c];
        for (int k = 0; k < HD; ++k) a = fmaf(sh[k], intW[k * 2 + c], a);
        sm[t] = a;
    }

    float acc = actb[t];
    for (int k = 0; k < HD; ++k) acc = fmaf(sh[k], actW[k * 64 + t], acc);
    __syncthreads();

    bool on = mask[(size_t)g * 64 + t] > 0;
    float x = acc * (1.0f / TEMP);
    float mx = on ? x : -INFINITY;
#pragma unroll
    for (int o = 32; o; o >>= 1) mx = fmaxf(mx, __shfl_xor(mx, o));
    float e = on ? __expf(x - mx) : 0.0f;
    float s = e;
#pragma unroll
    for (int o = 32; o; o >>= 1) s += __shfl_xor(s, o);
    float r = (s > 0.f) ? e / s : (1.0f / 64.0f);
    out[(size_t)g * 68 + 4 + t] = r;

    if (t == 0) {
        float a = sm[0] * (1.0f / TEMP), b = sm[1] * (1.0f / TEMP);
        float m2 = fmaxf(a, b);
        float e0 = __expf(a - m2), e1 = __expf(b - m2);
        out[(size_t)g * 68 + 0] = e0 / (e0 + e1);
        out[(size_t)g * 68 + 1] = e1 / (e0 + e1);
    } else if (t == 1) {
        float a = sm[2] * (1.0f / TEMP), b = sm[3] * (1.0f / TEMP);
        float m2 = fmaxf(a, b);
        float e0 = __expf(a - m2), e1 = __expf(b - m2);
        out[(size_t)g * 68 + 2] = e0 / (e0 + e1);
        out[(size_t)g * 68 + 3] = e1 / (e0 + e1);
    }
}

// ---------------------------------------------------------------------------
extern "C" void kernel_launch(void* const* d_in, const int* in_sizes, int n_in,
                              void* d_out, int out_size, void* d_ws, size_t ws_size,
                              hipStream_t stream)
{
    const int*   ids     = (const int*)d_in[0];
    const int*   mask    = (const int*)d_in[1];
    const float* Wb_iou  = (const float*)d_in[2];
    const float* Ub_iou  = (const float*)d_in[3];
    const float* bb_iou  = (const float*)d_in[4];
    const float* Wb_f    = (const float*)d_in[5];
    const float* Ub_f    = (const float*)d_in[6];
    const float* bb_f    = (const float*)d_in[7];
    const float* Wt_iou  = (const float*)d_in[8];
    const float* Ut_iou  = (const float*)d_in[9];
    const float* bt_iou  = (const float*)d_in[10];
    const float* Wt_f    = (const float*)d_in[11];
    const float* Ut_f    = (const float*)d_in[12];
    const float* bt_f    = (const float*)d_in[13];
    const float* ffn_W1  = (const float*)d_in[14];
    const float* ffn_b1  = (const float*)d_in[15];
    const float* ffn_W2  = (const float*)d_in[16];
    const float* ffn_b2  = (const float*)d_in[17];
    const float* hl_W    = (const float*)d_in[18];
    const float* hl_b    = (const float*)d_in[19];
    const float* int_W   = (const float*)d_in[20];
    const float* int_b   = (const float*)d_in[21];
    const float* act_W   = (const float*)d_in[22];
    const float* act_b   = (const float*)d_in[23];

    // ws: three bf16 state arrays, 25.16 MB each (75.5 MB total).
    bf16* h_all  = (bf16*)d_ws;
    bf16* c_all  = h_all + NHF;
    bf16* h3_all = c_all + NHF;
    bf16* t1     = c_all;    // alias: c dead after pass 2
    bf16* h4     = h_all;    // alias: h dead after pass 2

    // pass 1
    leaf1_k<<<(8192 * HD + 255) / 256, 256, 0, stream>>>(
        ids, Wb_iou, bb_iou, h_all, c_all);
    for (int d = 12; d >= 0; --d) {
        int n = 1 << d;
        int off = n - 1;
        dim3 grid(3, (n + 3) / 4);
        lvl1_k<<<grid, 256, 0, stream>>>(
            ids, h_all, c_all, Ub_iou, Ub_f, Wb_iou, bb_iou, Wb_f, bb_f, n, off);
    }

    // pass 2 (all nodes independent)
    lvl2_k<<<dim3(3, (NLEAF_OFF + 3) / 4), 256, 0, stream>>>(
        ids, h_all, c_all, h3_all, Ut_iou, Ut_f, Wt_iou, bt_iou, Wt_f, bt_f);
    leaf2_k<<<(8192 * HD + 255) / 256, 256, 0, stream>>>(
        ids, Wt_iou, bt_iou, h3_all);

    // FFN
    ffn_k<0><<<dim3(3, (N_NODES + 3) / 4), 256, 0, stream>>>(h3_all, ffn_W1, ffn_b1, t1);
    ffn_k<1><<<dim3(3, (N_NODES + 3) / 4), 256, 0, stream>>>(t1, ffn_W2, ffn_b2, h4);

    // heads
    heads_k<<<N_NODES, 64, 0, stream>>>(
        h4, mask, hl_W, hl_b, int_W, int_b, act_W, act_b, (float*)d_out);
}

// Round 5
// 1375.962 us; speedup vs baseline: 9.3328x; 9.3328x over previous
//
#include <hip/hip_runtime.h>
#include <hip/hip_bf16.h>

#define HD 768
#define N_NODES 16383
#define NLEAF_OFF 8191     // first leaf node index (level d=13 offset)
#define NHF 12582144       // N_NODES * HD
#define TEMP 3.0f

using bf16 = __hip_bfloat16;
typedef __attribute__((ext_vector_type(8))) short bf16x8;
typedef __attribute__((ext_vector_type(4))) float f32x4;

__device__ __forceinline__ float sigm(float x) { return 1.0f / (1.0f + __expf(-x)); }
__device__ __forceinline__ float b2f(bf16 v)   { return __bfloat162float(v); }
__device__ __forceinline__ bf16  f2b(float v)  { return __float2bfloat16(v); }

// ---------------------------------------------------------------------------
// Weight conversion: build bf16 B^T matrices once per launch.
// BT1 [3840][1536]: col n of pass-1 B. n<2304: Ub_iou[(l*768+h)*2304+n];
// else kk=(n-2304)/768, o=(n-2304)%768: Ub_f[((kk*2+l)*768+h)*768+o].
// ---------------------------------------------------------------------------
__global__ __launch_bounds__(256) void convT1_k(
    const float* __restrict__ Ub_iou, const float* __restrict__ Ub_f,
    bf16* __restrict__ BT)
{
    int idx = blockIdx.x * 256 + threadIdx.x;
    if (idx >= 3840 * 1536) return;
    int n = idx / 1536, k = idx - n * 1536;
    int l = (k >= 768);
    int h = k - l * 768;
    float v;
    if (n < 2304) {
        v = Ub_iou[(size_t)k * 2304 + n];
    } else {
        int c2 = n - 2304;
        int kk = c2 / 768, o = c2 - kk * 768;
        v = Ub_f[(((size_t)(kk * 2 + l)) * 768 + h) * 768 + o];
    }
    BT[idx] = f2b(v);
}

// BT2 [4608][2304]: n<2304: Ut_iou[k*2304+n]; else Ut_f[((kk*3+l)*768+h)*768+o]
__global__ __launch_bounds__(256) void convT2_k(
    const float* __restrict__ Ut_iou, const float* __restrict__ Ut_f,
    bf16* __restrict__ BT)
{
    int idx = blockIdx.x * 256 + threadIdx.x;
    if (idx >= 4608 * 2304) return;
    int n = idx / 2304, k = idx - n * 2304;
    int l = (k >= 768) + (k >= 1536);
    int h = k - l * 768;
    float v;
    if (n < 2304) {
        v = Ut_iou[(size_t)k * 2304 + n];
    } else {
        int c2 = n - 2304;
        int kk = c2 / 768, o = c2 - kk * 768;
        v = Ut_f[(((size_t)(kk * 3 + l)) * 768 + h) * 768 + o];
    }
    BT[idx] = f2b(v);
}

// WT [768][768] = W^T, bf16
__global__ __launch_bounds__(256) void convW_k(
    const float* __restrict__ W, bf16* __restrict__ WT)
{
    int idx = blockIdx.x * 256 + threadIdx.x;
    if (idx >= 768 * 768) return;
    int n = idx / 768, k = idx - n * 768;
    WT[idx] = f2b(W[(size_t)k * 768 + n]);
}

// ---------------------------------------------------------------------------
// A2 materialization for pass 2: row i (node g=g0+i) = [h(g), h(2g+1), h(2g+2)]
// ---------------------------------------------------------------------------
__global__ __launch_bounds__(256) void a2_k(
    const bf16* __restrict__ h_all, bf16* __restrict__ A2, int m, int g0)
{
    int idx = blockIdx.x * 256 + threadIdx.x;      // one per 8 elements
    if (idx >= m * 288) return;
    int i = idx / 288, c8 = idx - i * 288;
    int k = c8 * 8;
    int l = k / 768;
    int h = k - l * 768;
    int g = g0 + i;
    int node = (l == 0) ? g : (2 * g + l);
    *(uint4*)(A2 + (size_t)i * 2304 + k) =
        *(const uint4*)(h_all + (size_t)node * HD + h);
}

// ---------------------------------------------------------------------------
// bf16 MFMA GEMM: C[M x N] = A[M x K] @ BT[N x K]^T, fp32 accumulate.
// 128x128 tile, 4 waves (2x2 of 64x64), 16x16x32 MFMA, BK=32, padded LDS.
// EPI 0: write fp32 Cf. EPI 1: bias+relu -> bf16 Cb. EPI 2: bias -> bf16 Cb.
// Fragment layout (gfx950 16x16x32): A row = lane&15, k = (lane>>4)*8 + j;
// B col = lane&15, same k; D col = lane&15, row = (lane>>4)*4 + reg.
// ---------------------------------------------------------------------------
template <int EPI>
__global__ __launch_bounds__(256) void mm_k(
    const bf16* __restrict__ A, const bf16* __restrict__ BT,
    float* __restrict__ Cf, bf16* __restrict__ Cb,
    const float* __restrict__ bias,
    int M, int N, int K)
{
    __shared__ short As[128][40];
    __shared__ short Bs[128][40];

    int tid  = threadIdx.x;
    int lane = tid & 63;
    int wave = tid >> 6;
    int wr = wave >> 1, wc = wave & 1;
    int bx = blockIdx.x, by = blockIdx.y;

    f32x4 acc[4][4] = {};

    int srow = tid >> 1;             // 0..127
    int scol = (tid & 1) << 4;       // 0 or 16
    int ar = by * 128 + srow;
    int br = bx * 128 + srow;        // always < N (N multiple of 128)
    const bf16* Ap = A  + (size_t)ar * K + scol;
    const bf16* Bp = BT + (size_t)br * K + scol;
    bool aval = (ar < M);

    int fr = lane & 15;
    int fk = (lane >> 4) << 3;

    for (int kt = 0; kt < K; kt += 32) {
        uint4 av0 = {0, 0, 0, 0}, av1 = {0, 0, 0, 0};
        if (aval) {
            av0 = *(const uint4*)(Ap + kt);
            av1 = *(const uint4*)(Ap + kt + 8);
        }
        uint4 bv0 = *(const uint4*)(Bp + kt);
        uint4 bv1 = *(const uint4*)(Bp + kt + 8);
        *(uint4*)&As[srow][scol]     = av0;
        *(uint4*)&As[srow][scol + 8] = av1;
        *(uint4*)&Bs[srow][scol]     = bv0;
        *(uint4*)&Bs[srow][scol + 8] = bv1;
        __syncthreads();

        bf16x8 a[4], b[4];
#pragma unroll
        for (int m = 0; m < 4; m++)
            a[m] = *(const bf16x8*)&As[wr * 64 + m * 16 + fr][fk];
#pragma unroll
        for (int n = 0; n < 4; n++)
            b[n] = *(const bf16x8*)&Bs[wc * 64 + n * 16 + fr][fk];
#pragma unroll
        for (int m = 0; m < 4; m++)
#pragma unroll
            for (int n = 0; n < 4; n++)
                acc[m][n] = __builtin_amdgcn_mfma_f32_16x16x32_bf16(
                    a[m], b[n], acc[m][n], 0, 0, 0);
        __syncthreads();
    }

    int rbase = by * 128 + wr * 64 + ((lane >> 4) << 2);
    int cbase = bx * 128 + wc * 64 + fr;
#pragma unroll
    for (int m = 0; m < 4; m++) {
#pragma unroll
        for (int r = 0; r < 4; r++) {
            int row = rbase + m * 16 + r;
            if (row >= M) continue;
#pragma unroll
            for (int n = 0; n < 4; n++) {
                int col = cbase + n * 16;
                float v = acc[m][n][r];
                if constexpr (EPI == 1) {
                    v = fmaxf(v + bias[col], 0.f);
                    Cb[(size_t)row * N + col] = f2b(v);
                } else if constexpr (EPI == 2) {
                    v = v + bias[col];
                    Cb[(size_t)row * N + col] = f2b(v);
                } else {
                    Cf[(size_t)row * N + col] = v;
                }
            }
        }
    }
}

// ---------------------------------------------------------------------------
// Leaves, pass 1
// ---------------------------------------------------------------------------
__global__ __launch_bounds__(256) void leaf1_k(
    const int* __restrict__ ids,
    const float* __restrict__ Wb, const float* __restrict__ bb,
    bf16* __restrict__ h_all, bf16* __restrict__ c_all)
{
    int idx = blockIdx.x * blockDim.x + threadIdx.x;
    if (idx >= 8192 * HD) return;
    int i = idx / HD, j = idx - i * HD;
    int g = NLEAF_OFF + i;
    int id = ids[g];
    const float* w = Wb + (size_t)id * 3 * HD;
    float iv = sigm(w[j] + bb[j]);
    float ov = sigm(w[HD + j] + bb[HD + j]);
    float gv = tanhf(w[2 * HD + j] + bb[2 * HD + j]);
    float c = iv * gv;
    h_all[(size_t)g * HD + j] = f2b(ov * tanhf(c));
    c_all[(size_t)g * HD + j] = f2b(c);
}

// Leaves, pass 2
__global__ __launch_bounds__(256) void leaf2_k(
    const int* __restrict__ ids,
    const float* __restrict__ Wt, const float* __restrict__ bt,
    bf16* __restrict__ h3_all)
{
    int idx = blockIdx.x * blockDim.x + threadIdx.x;
    if (idx >= 8192 * HD) return;
    int i = idx / HD, j = idx - i * HD;
    int g = NLEAF_OFF + i;
    int id = ids[g];
    const float* w = Wt + (size_t)id * 3 * HD;
    float iv = sigm(w[j] + bt[j]);
    float ov = sigm(w[HD + j] + bt[HD + j]);
    float gv = tanhf(w[2 * HD + j] + bt[2 * HD + j]);
    float c = iv * gv;
    h3_all[(size_t)g * HD + j] = f2b(ov * tanhf(c));
}

// ---------------------------------------------------------------------------
// Pass-1 cell: S(m x 3840) -> bf16 h,c for nodes [offAbs, offAbs+m)
// ---------------------------------------------------------------------------
__global__ __launch_bounds__(256) void cell1_k(
    const int* __restrict__ ids, const float* __restrict__ S,
    const float* __restrict__ Wiou, const float* __restrict__ biou,
    const float* __restrict__ Wf, const float* __restrict__ bfv,
    bf16* __restrict__ h_all, bf16* __restrict__ c_all,
    int m, int offAbs)
{
    int idx = blockIdx.x * blockDim.x + threadIdx.x;
    if (idx >= m * HD) return;
    int i = idx / HD, j = idx - i * HD;
    int g = offAbs + i;
    int id = ids[g];
    const float* s = S + (size_t)i * 3840;
    const float* w = Wiou + (size_t)id * 2304;
    float iv = sigm(s[j] + w[j] + biou[j]);
    float ov = sigm(s[HD + j] + w[HD + j] + biou[HD + j]);
    float gv = tanhf(s[2 * HD + j] + w[2 * HD + j] + biou[2 * HD + j]);
    float xf = Wf[(size_t)id * HD + j] + bfv[j];
    float f0 = sigm(s[3 * HD + j] + xf);
    float f1 = sigm(s[4 * HD + j] + xf);
    float c = iv * gv
            + f0 * b2f(c_all[(size_t)(2 * g + 1) * HD + j])
            + f1 * b2f(c_all[(size_t)(2 * g + 2) * HD + j]);
    h_all[(size_t)g * HD + j] = f2b(ov * tanhf(c));
    c_all[(size_t)g * HD + j] = f2b(c);
}

// ---------------------------------------------------------------------------
// Pass-2 cell: S(m x 4608) -> bf16 h3 for nodes [g0, g0+m)
// ---------------------------------------------------------------------------
__global__ __launch_bounds__(256) void cell2_k(
    const int* __restrict__ ids, const float* __restrict__ S,
    const float* __restrict__ Wiou, const float* __restrict__ biou,
    const float* __restrict__ Wf, const float* __restrict__ bfv,
    const bf16* __restrict__ c_all, bf16* __restrict__ h3_all,
    int m, int g0)
{
    int idx = blockIdx.x * blockDim.x + threadIdx.x;
    if (idx >= m * HD) return;
    int i = idx / HD, j = idx - i * HD;
    int g = g0 + i;
    int id = ids[g];
    const float* s = S + (size_t)i * 4608;
    const float* w = Wiou + (size_t)id * 2304;
    float iv = sigm(s[j] + w[j] + biou[j]);
    float ov = sigm(s[HD + j] + w[HD + j] + biou[HD + j]);
    float gv = tanhf(s[2 * HD + j] + w[2 * HD + j] + biou[2 * HD + j]);
    float xf = Wf[(size_t)id * HD + j] + bfv[j];
    float f0 = sigm(s[3 * HD + j] + xf);
    float f1 = sigm(s[4 * HD + j] + xf);
    float f2 = sigm(s[5 * HD + j] + xf);
    float c = iv * gv
            + f0 * b2f(c_all[(size_t)g * HD + j])
            + f1 * b2f(c_all[(size_t)(2 * g + 1) * HD + j])
            + f2 * b2f(c_all[(size_t)(2 * g + 2) * HD + j]);
    h3_all[(size_t)g * HD + j] = f2b(ov * tanhf(c));
}

// ---------------------------------------------------------------------------
// Heads: one 64-lane wave per node; fp32 out.
// ---------------------------------------------------------------------------
__global__ __launch_bounds__(64) void heads_k(
    const bf16* __restrict__ h4, const int* __restrict__ mask,
    const float* __restrict__ hlW, const float* __restrict__ hlb,
    const float* __restrict__ intW, const float* __restrict__ intb,
    const float* __restrict__ actW, const float* __restrict__ actb,
    float* __restrict__ out)
{
    int g = blockIdx.x;
    int t = threadIdx.x;
    __shared__ float sh[HD];
    __shared__ float sm[4];

    for (int k = t; k < HD; k += 64)
        sh[k] = b2f(h4[(size_t)g * HD + k]);
    __syncthreads();

    if (t < 2) {
        float a = hlb[t];
        for (int k = 0; k < HD; ++k) a = fmaf(sh[k], hlW[k * 2 + t], a);
        sm[t] = a;
    } else if (t < 4) {
        int c = t - 2;
        float a = intb[c];
        for (int k = 0; k < HD; ++k) a = fmaf(sh[k], intW[k * 2 + c], a);
        sm[t] = a;
    }

    float acc = actb[t];
    for (int k = 0; k < HD; ++k) acc = fmaf(sh[k], actW[k * 64 + t], acc);
    __syncthreads();

    bool on = mask[(size_t)g * 64 + t] > 0;
    float x = acc * (1.0f / TEMP);
    float mx = on ? x : -INFINITY;
#pragma unroll
    for (int o = 32; o; o >>= 1) mx = fmaxf(mx, __shfl_xor(mx, o));
    float e = on ? __expf(x - mx) : 0.0f;
    float s = e;
#pragma unroll
    for (int o = 32; o; o >>= 1) s += __shfl_xor(s, o);
    float r = (s > 0.f) ? e / s : (1.0f / 64.0f);
    out[(size_t)g * 68 + 4 + t] = r;

    if (t == 0) {
        float a = sm[0] * (1.0f / TEMP), b = sm[1] * (1.0f / TEMP);
        float m2 = fmaxf(a, b);
        float e0 = __expf(a - m2), e1 = __expf(b - m2);
        out[(size_t)g * 68 + 0] = e0 / (e0 + e1);
        out[(size_t)g * 68 + 1] = e1 / (e0 + e1);
    } else if (t == 1) {
        float a = sm[2] * (1.0f / TEMP), b = sm[3] * (1.0f / TEMP);
        float m2 = fmaxf(a, b);
        float e0 = __expf(a - m2), e1 = __expf(b - m2);
        out[(size_t)g * 68 + 2] = e0 / (e0 + e1);
        out[(size_t)g * 68 + 3] = e1 / (e0 + e1);
    }
}

// ---------------------------------------------------------------------------
extern "C" void kernel_launch(void* const* d_in, const int* in_sizes, int n_in,
                              void* d_out, int out_size, void* d_ws, size_t ws_size,
                              hipStream_t stream)
{
    const int*   ids     = (const int*)d_in[0];
    const int*   mask    = (const int*)d_in[1];
    const float* Wb_iou  = (const float*)d_in[2];
    const float* Ub_iou  = (const float*)d_in[3];
    const float* bb_iou  = (const float*)d_in[4];
    const float* Wb_f    = (const float*)d_in[5];
    const float* Ub_f    = (const float*)d_in[6];
    const float* bb_f    = (const float*)d_in[7];
    const float* Wt_iou  = (const float*)d_in[8];
    const float* Ut_iou  = (const float*)d_in[9];
    const float* bt_iou  = (const float*)d_in[10];
    const float* Wt_f    = (const float*)d_in[11];
    const float* Ut_f    = (const float*)d_in[12];
    const float* bt_f    = (const float*)d_in[13];
    const float* ffn_W1  = (const float*)d_in[14];
    const float* ffn_b1  = (const float*)d_in[15];
    const float* ffn_W2  = (const float*)d_in[16];
    const float* ffn_b2  = (const float*)d_in[17];
    const float* hl_W    = (const float*)d_in[18];
    const float* hl_b    = (const float*)d_in[19];
    const float* int_W   = (const float*)d_in[20];
    const float* int_b   = (const float*)d_in[21];
    const float* act_W   = (const float*)d_in[22];
    const float* act_b   = (const float*)d_in[23];

    // ---- workspace layout ----
    char* p = (char*)d_ws;
    bf16* h_all  = (bf16*)p; p += (size_t)NHF * 2;
    bf16* c_all  = (bf16*)p; p += (size_t)NHF * 2;
    bf16* h3_all = (bf16*)p; p += (size_t)NHF * 2;
    bf16* BT1 = (bf16*)p; p += (size_t)3840 * 1536 * 2;
    bf16* BT2 = (bf16*)p; p += (size_t)4608 * 2304 * 2;
    bf16* W1T = (bf16*)p; p += (size_t)768 * 768 * 2;
    bf16* W2T = (bf16*)p; p += (size_t)768 * 768 * 2;
    bf16* t1  = c_all;   // FFN hidden aliases dead c
    bf16* h4  = h_all;   // FFN out aliases dead h

    size_t used = (size_t)(p - (char*)d_ws);
    size_t rem = (ws_size > used + 256) ? (ws_size - used - 256) : 0;
    long Rl = (long)(rem / 23040);          // per row: A2 4608 B + S 18432 B
    Rl = (Rl / 128) * 128;
    if (Rl < 128) Rl = 128;
    if (Rl > 4224) Rl = 4224;
    int R = (int)Rl;
    bf16*  A2 = (bf16*)p;
    float* S  = (float*)(p + (size_t)R * 2304 * 2);
    int R1 = (int)(((long)R * 6) / 5);      // pass-1 rows that fit in S (3840 f32/row)

    // ---- weight conversions (bf16 B^T) ----
    convT1_k<<<(3840 * 1536 + 255) / 256, 256, 0, stream>>>(Ub_iou, Ub_f, BT1);
    convT2_k<<<(4608 * 2304 + 255) / 256, 256, 0, stream>>>(Ut_iou, Ut_f, BT2);
    convW_k<<<(768 * 768 + 255) / 256, 256, 0, stream>>>(ffn_W1, W1T);
    convW_k<<<(768 * 768 + 255) / 256, 256, 0, stream>>>(ffn_W2, W2T);

    // ---- pass 1 ----
    leaf1_k<<<(8192 * HD + 255) / 256, 256, 0, stream>>>(ids, Wb_iou, bb_iou, h_all, c_all);
    for (int d = 12; d >= 0; --d) {
        int n = 1 << d;
        int off = n - 1;
        int childoff = 2 * n - 1;
        for (int r0 = 0; r0 < n; r0 += R1) {
            int m = n - r0; if (m > R1) m = R1;
            mm_k<0><<<dim3(30, (m + 127) / 128), 256, 0, stream>>>(
                h_all + (size_t)(childoff + 2 * r0) * HD, BT1, S, nullptr, nullptr,
                m, 3840, 1536);
            cell1_k<<<(m * HD + 255) / 256, 256, 0, stream>>>(
                ids, S, Wb_iou, bb_iou, Wb_f, bb_f, h_all, c_all, m, off + r0);
        }
    }

    // ---- pass 2 (non-leaf), chunked ----
    for (int g0 = 0; g0 < NLEAF_OFF; g0 += R) {
        int m = NLEAF_OFF - g0; if (m > R) m = R;
        a2_k<<<(m * 288 + 255) / 256, 256, 0, stream>>>(h_all, A2, m, g0);
        mm_k<0><<<dim3(36, (m + 127) / 128), 256, 0, stream>>>(
            A2, BT2, S, nullptr, nullptr, m, 4608, 2304);
        cell2_k<<<(m * HD + 255) / 256, 256, 0, stream>>>(
            ids, S, Wt_iou, bt_iou, Wt_f, bt_f, c_all, h3_all, m, g0);
    }
    leaf2_k<<<(8192 * HD + 255) / 256, 256, 0, stream>>>(ids, Wt_iou, bt_iou, h3_all);

    // ---- FFN (bias/relu fused epilogues, bf16 out) ----
    mm_k<1><<<dim3(6, 128), 256, 0, stream>>>(
        h3_all, W1T, nullptr, t1, ffn_b1, N_NODES, 768, 768);
    mm_k<2><<<dim3(6, 128), 256, 0, stream>>>(
        t1, W2T, nullptr, h4, ffn_b2, N_NODES, 768, 768);

    // ---- heads ----
    heads_k<<<N_NODES, 64, 0, stream>>>(
        h4, mask, hl_W, hl_b, int_W, int_b, act_W, act_b, (float*)d_out);
}

// Round 6
// 1119.419 us; speedup vs baseline: 11.4717x; 1.2292x over previous
//
#include <hip/hip_runtime.h>
#include <hip/hip_bf16.h>

#define HD 768
#define N_NODES 16383
#define NLEAF_OFF 8191     // first leaf node index (level d=13 offset)
#define NHF 12582144       // N_NODES * HD
#define TEMP 3.0f

using bf16 = __hip_bfloat16;
typedef __attribute__((ext_vector_type(8))) short bf16x8;
typedef __attribute__((ext_vector_type(4))) float f32x4;

__device__ __forceinline__ float sigm(float x) { return 1.0f / (1.0f + __expf(-x)); }
__device__ __forceinline__ float b2f(bf16 v)   { return __bfloat162float(v); }
__device__ __forceinline__ bf16  f2b(float v)  { return __float2bfloat16(v); }

// async global->LDS, 16B per lane. LDS dest = wave-uniform base + lane*16.
__device__ __forceinline__ void gload16(const void* g, void* l) {
    __builtin_amdgcn_global_load_lds(
        (const __attribute__((address_space(1))) unsigned int*)g,
        (__attribute__((address_space(3))) unsigned int*)l, 16, 0, 0);
}

// ---------------------------------------------------------------------------
// Weight conversion: bf16 B^T matrices, built once per launch.
// ---------------------------------------------------------------------------
__global__ __launch_bounds__(256) void convT1_k(
    const float* __restrict__ Ub_iou, const float* __restrict__ Ub_f,
    bf16* __restrict__ BT)
{
    int idx = blockIdx.x * 256 + threadIdx.x;
    if (idx >= 3840 * 1536) return;
    int n = idx / 1536, k = idx - n * 1536;
    int l = (k >= 768);
    int h = k - l * 768;
    float v;
    if (n < 2304) {
        v = Ub_iou[(size_t)k * 2304 + n];
    } else {
        int c2 = n - 2304;
        int kk = c2 / 768, o = c2 - kk * 768;
        v = Ub_f[(((size_t)(kk * 2 + l)) * 768 + h) * 768 + o];
    }
    BT[idx] = f2b(v);
}

__global__ __launch_bounds__(256) void convT2_k(
    const float* __restrict__ Ut_iou, const float* __restrict__ Ut_f,
    bf16* __restrict__ BT)
{
    int idx = blockIdx.x * 256 + threadIdx.x;
    if (idx >= 4608 * 2304) return;
    int n = idx / 2304, k = idx - n * 2304;
    int l = (k >= 768) + (k >= 1536);
    int h = k - l * 768;
    float v;
    if (n < 2304) {
        v = Ut_iou[(size_t)k * 2304 + n];
    } else {
        int c2 = n - 2304;
        int kk = c2 / 768, o = c2 - kk * 768;
        v = Ut_f[(((size_t)(kk * 3 + l)) * 768 + h) * 768 + o];
    }
    BT[idx] = f2b(v);
}

__global__ __launch_bounds__(256) void convW_k(
    const float* __restrict__ W, bf16* __restrict__ WT)
{
    int idx = blockIdx.x * 256 + threadIdx.x;
    if (idx >= 768 * 768) return;
    int n = idx / 768, k = idx - n * 768;
    WT[idx] = f2b(W[(size_t)k * 768 + n]);
}

// Head weights packed: WhT[128][768]; cols 0-1 hl, 2-3 int, 4-67 act, rest 0.
__global__ __launch_bounds__(256) void convH_k(
    const float* __restrict__ hlW, const float* __restrict__ intW,
    const float* __restrict__ actW, bf16* __restrict__ WhT)
{
    int idx = blockIdx.x * 256 + threadIdx.x;
    if (idx >= 128 * 768) return;
    int n = idx / 768, k = idx - n * 768;
    float v = 0.f;
    if (n < 2)       v = hlW[(size_t)k * 2 + n];
    else if (n < 4)  v = intW[(size_t)k * 2 + (n - 2)];
    else if (n < 68) v = actW[(size_t)k * 64 + (n - 4)];
    WhT[idx] = f2b(v);
}

// ---------------------------------------------------------------------------
// A2 materialization for pass 2: row i (node g=g0+i) = [h(g), h(2g+1), h(2g+2)]
// ---------------------------------------------------------------------------
__global__ __launch_bounds__(256) void a2_k(
    const bf16* __restrict__ h_all, bf16* __restrict__ A2, int m, int g0)
{
    int idx = blockIdx.x * 256 + threadIdx.x;      // one per 8 elements
    if (idx >= m * 288) return;
    int i = idx / 288, c8 = idx - i * 288;
    int k = c8 * 8;
    int l = k / 768;
    int h = k - l * 768;
    int g = g0 + i;
    int node = (l == 0) ? g : (2 * g + l);
    *(uint4*)(A2 + (size_t)i * 2304 + k) =
        *(const uint4*)(h_all + (size_t)node * HD + h);
}

// ---------------------------------------------------------------------------
// bf16 MFMA GEMM (m97 structure): C[M x N] = A[M x K] @ BT[N x K]^T.
// 128x128 tile, 4 waves (2x2 of 64x64), BK=32, linear LDS [128][32] bf16,
// staged via global_load_lds dwordx4 (wave-uniform LDS base + lane*16).
// OOB A rows clamp to row M-1 (garbage confined to unwritten C rows).
// EPI 0: fp32 Cf. EPI 1: bias+relu -> bf16 Cb. EPI 2: bias -> bf16 Cb.
// ---------------------------------------------------------------------------
template <int EPI>
__global__ __launch_bounds__(256) void mm_k(
    const bf16* __restrict__ A, const bf16* __restrict__ BT,
    float* __restrict__ Cf, bf16* __restrict__ Cb,
    const float* __restrict__ bias,
    int M, int N, int K)
{
    __shared__ short As[128 * 32];
    __shared__ short Bs[128 * 32];

    int tid  = threadIdx.x;
    int lane = tid & 63;
    int wave = tid >> 6;                 // 0..3
    int wr = wave >> 1, wc = wave & 1;
    int bx = blockIdx.x, by = blockIdx.y;

    f32x4 acc[4][4] = {};

    // staging: wave w, instr q covers rows [w*16 + q*64, +16), 4 lanes/row
    int sr  = lane >> 2;                 // row within 16-row group
    int sc8 = (lane & 3) * 8;            // bf16 col offset 0/8/16/24
    int arow0 = by * 128 + wave * 16 + sr;
    int arow1 = arow0 + 64;
    if (arow0 > M - 1) arow0 = M - 1;
    if (arow1 > M - 1) arow1 = M - 1;
    const bf16* gA0 = A + (size_t)arow0 * K + sc8;
    const bf16* gA1 = A + (size_t)arow1 * K + sc8;
    const bf16* gB0 = BT + (size_t)(bx * 128 + wave * 16 + sr) * K + sc8;
    const bf16* gB1 = BT + (size_t)(bx * 128 + wave * 16 + sr + 64) * K + sc8;
    short* lA0 = As + wave * 512;        // wave-uniform bases (lane*16B added by HW)
    short* lA1 = As + wave * 512 + 2048;
    short* lB0 = Bs + wave * 512;
    short* lB1 = Bs + wave * 512 + 2048;

    int fr = lane & 15;
    int fk = (lane >> 4) << 3;           // 0,8,16,24
    const short* pAf = As + (wr * 64 + fr) * 32 + fk;
    const short* pBf = Bs + (wc * 64 + fr) * 32 + fk;

    for (int kt = 0; kt < K; kt += 32) {
        gload16(gA0 + kt, lA0);
        gload16(gA1 + kt, lA1);
        gload16(gB0 + kt, lB0);
        gload16(gB1 + kt, lB1);
        __syncthreads();

        bf16x8 a[4], b[4];
#pragma unroll
        for (int m = 0; m < 4; m++) a[m] = *(const bf16x8*)(pAf + m * 512);
#pragma unroll
        for (int n = 0; n < 4; n++) b[n] = *(const bf16x8*)(pBf + n * 512);
#pragma unroll
        for (int m = 0; m < 4; m++)
#pragma unroll
            for (int n = 0; n < 4; n++)
                acc[m][n] = __builtin_amdgcn_mfma_f32_16x16x32_bf16(
                    a[m], b[n], acc[m][n], 0, 0, 0);
        __syncthreads();
    }

    int rbase = by * 128 + wr * 64 + ((lane >> 4) << 2);
    int cbase = bx * 128 + wc * 64 + fr;
#pragma unroll
    for (int m = 0; m < 4; m++) {
#pragma unroll
        for (int r = 0; r < 4; r++) {
            int row = rbase + m * 16 + r;
            if (row >= M) continue;
#pragma unroll
            for (int n = 0; n < 4; n++) {
                int col = cbase + n * 16;
                float v = acc[m][n][r];
                if constexpr (EPI == 1) {
                    v = fmaxf(v + bias[col], 0.f);
                    Cb[(size_t)row * N + col] = f2b(v);
                } else if constexpr (EPI == 2) {
                    v = v + bias[col];
                    Cb[(size_t)row * N + col] = f2b(v);
                } else {
                    Cf[(size_t)row * N + col] = v;
                }
            }
        }
    }
}

// ---------------------------------------------------------------------------
// Leaves, pass 1
// ---------------------------------------------------------------------------
__global__ __launch_bounds__(256) void leaf1_k(
    const int* __restrict__ ids,
    const float* __restrict__ Wb, const float* __restrict__ bb,
    bf16* __restrict__ h_all, bf16* __restrict__ c_all)
{
    int idx = blockIdx.x * blockDim.x + threadIdx.x;
    if (idx >= 8192 * HD) return;
    int i = idx / HD, j = idx - i * HD;
    int g = NLEAF_OFF + i;
    int id = ids[g];
    const float* w = Wb + (size_t)id * 3 * HD;
    float iv = sigm(w[j] + bb[j]);
    float ov = sigm(w[HD + j] + bb[HD + j]);
    float gv = tanhf(w[2 * HD + j] + bb[2 * HD + j]);
    float c = iv * gv;
    h_all[(size_t)g * HD + j] = f2b(ov * tanhf(c));
    c_all[(size_t)g * HD + j] = f2b(c);
}

// Leaves, pass 2
__global__ __launch_bounds__(256) void leaf2_k(
    const int* __restrict__ ids,
    const float* __restrict__ Wt, const float* __restrict__ bt,
    bf16* __restrict__ h3_all)
{
    int idx = blockIdx.x * blockDim.x + threadIdx.x;
    if (idx >= 8192 * HD) return;
    int i = idx / HD, j = idx - i * HD;
    int g = NLEAF_OFF + i;
    int id = ids[g];
    const float* w = Wt + (size_t)id * 3 * HD;
    float iv = sigm(w[j] + bt[j]);
    float ov = sigm(w[HD + j] + bt[HD + j]);
    float gv = tanhf(w[2 * HD + j] + bt[2 * HD + j]);
    float c = iv * gv;
    h3_all[(size_t)g * HD + j] = f2b(ov * tanhf(c));
}

// ---------------------------------------------------------------------------
// Pass-1 cell: S(m x 3840) -> bf16 h,c for nodes [offAbs, offAbs+m)
// ---------------------------------------------------------------------------
__global__ __launch_bounds__(256) void cell1_k(
    const int* __restrict__ ids, const float* __restrict__ S,
    const float* __restrict__ Wiou, const float* __restrict__ biou,
    const float* __restrict__ Wf, const float* __restrict__ bfv,
    bf16* __restrict__ h_all, bf16* __restrict__ c_all,
    int m, int offAbs)
{
    int idx = blockIdx.x * blockDim.x + threadIdx.x;
    if (idx >= m * HD) return;
    int i = idx / HD, j = idx - i * HD;
    int g = offAbs + i;
    int id = ids[g];
    const float* s = S + (size_t)i * 3840;
    const float* w = Wiou + (size_t)id * 2304;
    float iv = sigm(s[j] + w[j] + biou[j]);
    float ov = sigm(s[HD + j] + w[HD + j] + biou[HD + j]);
    float gv = tanhf(s[2 * HD + j] + w[2 * HD + j] + biou[2 * HD + j]);
    float xf = Wf[(size_t)id * HD + j] + bfv[j];
    float f0 = sigm(s[3 * HD + j] + xf);
    float f1 = sigm(s[4 * HD + j] + xf);
    float c = iv * gv
            + f0 * b2f(c_all[(size_t)(2 * g + 1) * HD + j])
            + f1 * b2f(c_all[(size_t)(2 * g + 2) * HD + j]);
    h_all[(size_t)g * HD + j] = f2b(ov * tanhf(c));
    c_all[(size_t)g * HD + j] = f2b(c);
}

// ---------------------------------------------------------------------------
// Pass-2 cell: S(m x 4608) -> bf16 h3 for nodes [g0, g0+m)
// ---------------------------------------------------------------------------
__global__ __launch_bounds__(256) void cell2_k(
    const int* __restrict__ ids, const float* __restrict__ S,
    const float* __restrict__ Wiou, const float* __restrict__ biou,
    const float* __restrict__ Wf, const float* __restrict__ bfv,
    const bf16* __restrict__ c_all, bf16* __restrict__ h3_all,
    int m, int g0)
{
    int idx = blockIdx.x * blockDim.x + threadIdx.x;
    if (idx >= m * HD) return;
    int i = idx / HD, j = idx - i * HD;
    int g = g0 + i;
    int id = ids[g];
    const float* s = S + (size_t)i * 4608;
    const float* w = Wiou + (size_t)id * 2304;
    float iv = sigm(s[j] + w[j] + biou[j]);
    float ov = sigm(s[HD + j] + w[HD + j] + biou[HD + j]);
    float gv = tanhf(s[2 * HD + j] + w[2 * HD + j] + biou[2 * HD + j]);
    float xf = Wf[(size_t)id * HD + j] + bfv[j];
    float f0 = sigm(s[3 * HD + j] + xf);
    float f1 = sigm(s[4 * HD + j] + xf);
    float f2 = sigm(s[5 * HD + j] + xf);
    float c = iv * gv
            + f0 * b2f(c_all[(size_t)g * HD + j])
            + f1 * b2f(c_all[(size_t)(2 * g + 1) * HD + j])
            + f2 * b2f(c_all[(size_t)(2 * g + 2) * HD + j]);
    h3_all[(size_t)g * HD + j] = f2b(ov * tanhf(c));
}

// ---------------------------------------------------------------------------
// Head softmaxes from precomputed logits L[g][128] (cols 0-1 hl, 2-3 int,
// 4-67 act). One wave per node, 4 nodes per block. fp32 out rows of 68.
// ---------------------------------------------------------------------------
__global__ __launch_bounds__(256) void hsm_k(
    const float* __restrict__ L, const int* __restrict__ mask,
    const float* __restrict__ hlb, const float* __restrict__ intb,
    const float* __restrict__ actb, float* __restrict__ out)
{
    int g = blockIdx.x * 4 + (threadIdx.x >> 6);
    if (g >= N_NODES) return;
    int t = threadIdx.x & 63;
    const float* lr = L + (size_t)g * 128;

    bool on = mask[(size_t)g * 64 + t] > 0;
    float x = (lr[4 + t] + actb[t]) * (1.0f / TEMP);
    float mx = on ? x : -INFINITY;
#pragma unroll
    for (int o = 32; o; o >>= 1) mx = fmaxf(mx, __shfl_xor(mx, o));
    float e = on ? __expf(x - mx) : 0.0f;
    float s = e;
#pragma unroll
    for (int o = 32; o; o >>= 1) s += __shfl_xor(s, o);
    float r = (s > 0.f) ? e / s : (1.0f / 64.0f);
    out[(size_t)g * 68 + 4 + t] = r;

    if (t == 0) {
        float a = (lr[0] + hlb[0]) * (1.0f / TEMP);
        float b = (lr[1] + hlb[1]) * (1.0f / TEMP);
        float m2 = fmaxf(a, b);
        float e0 = __expf(a - m2), e1 = __expf(b - m2);
        out[(size_t)g * 68 + 0] = e0 / (e0 + e1);
        out[(size_t)g * 68 + 1] = e1 / (e0 + e1);
    } else if (t == 1) {
        float a = (lr[2] + intb[0]) * (1.0f / TEMP);
        float b = (lr[3] + intb[1]) * (1.0f / TEMP);
        float m2 = fmaxf(a, b);
        float e0 = __expf(a - m2), e1 = __expf(b - m2);
        out[(size_t)g * 68 + 2] = e0 / (e0 + e1);
        out[(size_t)g * 68 + 3] = e1 / (e0 + e1);
    }
}

// ---------------------------------------------------------------------------
extern "C" void kernel_launch(void* const* d_in, const int* in_sizes, int n_in,
                              void* d_out, int out_size, void* d_ws, size_t ws_size,
                              hipStream_t stream)
{
    const int*   ids     = (const int*)d_in[0];
    const int*   mask    = (const int*)d_in[1];
    const float* Wb_iou  = (const float*)d_in[2];
    const float* Ub_iou  = (const float*)d_in[3];
    const float* bb_iou  = (const float*)d_in[4];
    const float* Wb_f    = (const float*)d_in[5];
    const float* Ub_f    = (const float*)d_in[6];
    const float* bb_f    = (const float*)d_in[7];
    const float* Wt_iou  = (const float*)d_in[8];
    const float* Ut_iou  = (const float*)d_in[9];
    const float* bt_iou  = (const float*)d_in[10];
    const float* Wt_f    = (const float*)d_in[11];
    const float* Ut_f    = (const float*)d_in[12];
    const float* bt_f    = (const float*)d_in[13];
    const float* ffn_W1  = (const float*)d_in[14];
    const float* ffn_b1  = (const float*)d_in[15];
    const float* ffn_W2  = (const float*)d_in[16];
    const float* ffn_b2  = (const float*)d_in[17];
    const float* hl_W    = (const float*)d_in[18];
    const float* hl_b    = (const float*)d_in[19];
    const float* int_W   = (const float*)d_in[20];
    const float* int_b   = (const float*)d_in[21];
    const float* act_W   = (const float*)d_in[22];
    const float* act_b   = (const float*)d_in[23];

    // ---- workspace layout ----
    char* p = (char*)d_ws;
    bf16* h_all  = (bf16*)p; p += (size_t)NHF * 2;
    bf16* c_all  = (bf16*)p; p += (size_t)NHF * 2;
    bf16* h3_all = (bf16*)p; p += (size_t)NHF * 2;
    bf16* BT1 = (bf16*)p; p += (size_t)3840 * 1536 * 2;
    bf16* BT2 = (bf16*)p; p += (size_t)4608 * 2304 * 2;
    bf16* W1T = (bf16*)p; p += (size_t)768 * 768 * 2;
    bf16* W2T = (bf16*)p; p += (size_t)768 * 768 * 2;
    bf16* WhT = (bf16*)p; p += (size_t)128 * 768 * 2;
    bf16* t1  = c_all;                 // FFN hidden aliases dead c
    bf16* h4  = h_all;                 // FFN out aliases dead h
    float* Lg = (float*)h3_all;        // head logits alias dead h3 (8.4 MB < 25 MB)

    size_t used = (size_t)(p - (char*)d_ws);
    size_t rem = (ws_size > used + 256) ? (ws_size - used - 256) : 0;
    long Rl = (long)(rem / 23040);     // per row: A2 4608 B + S 18432 B
    Rl = (Rl / 128) * 128;
    if (Rl < 128) Rl = 128;
    if (Rl > 4224) Rl = 4224;
    int R = (int)Rl;
    bf16*  A2 = (bf16*)p;
    float* S  = (float*)(p + (size_t)R * 2304 * 2);
    int R1 = (int)(((long)R * 6) / 5); // pass-1 rows in S (3840 f32/row)

    // ---- weight conversions (bf16 B^T) ----
    convT1_k<<<(3840 * 1536 + 255) / 256, 256, 0, stream>>>(Ub_iou, Ub_f, BT1);
    convT2_k<<<(4608 * 2304 + 255) / 256, 256, 0, stream>>>(Ut_iou, Ut_f, BT2);
    convW_k<<<(768 * 768 + 255) / 256, 256, 0, stream>>>(ffn_W1, W1T);
    convW_k<<<(768 * 768 + 255) / 256, 256, 0, stream>>>(ffn_W2, W2T);
    convH_k<<<(128 * 768 + 255) / 256, 256, 0, stream>>>(hl_W, int_W, act_W, WhT);

    // ---- pass 1 ----
    leaf1_k<<<(8192 * HD + 255) / 256, 256, 0, stream>>>(ids, Wb_iou, bb_iou, h_all, c_all);
    for (int d = 12; d >= 0; --d) {
        int n = 1 << d;
        int off = n - 1;
        int childoff = 2 * n - 1;
        for (int r0 = 0; r0 < n; r0 += R1) {
            int m = n - r0; if (m > R1) m = R1;
            mm_k<0><<<dim3(30, (m + 127) / 128), 256, 0, stream>>>(
                h_all + (size_t)(childoff + 2 * r0) * HD, BT1, S, nullptr, nullptr,
                m, 3840, 1536);
            cell1_k<<<(m * HD + 255) / 256, 256, 0, stream>>>(
                ids, S, Wb_iou, bb_iou, Wb_f, bb_f, h_all, c_all, m, off + r0);
        }
    }

    // ---- pass 2 (non-leaf), chunked ----
    for (int g0 = 0; g0 < NLEAF_OFF; g0 += R) {
        int m = NLEAF_OFF - g0; if (m > R) m = R;
        a2_k<<<(m * 288 + 255) / 256, 256, 0, stream>>>(h_all, A2, m, g0);
        mm_k<0><<<dim3(36, (m + 127) / 128), 256, 0, stream>>>(
            A2, BT2, S, nullptr, nullptr, m, 4608, 2304);
        cell2_k<<<(m * HD + 255) / 256, 256, 0, stream>>>(
            ids, S, Wt_iou, bt_iou, Wt_f, bt_f, c_all, h3_all, m, g0);
    }
    leaf2_k<<<(8192 * HD + 255) / 256, 256, 0, stream>>>(ids, Wt_iou, bt_iou, h3_all);

    // ---- FFN (bias/relu fused epilogues, bf16 out) ----
    mm_k<1><<<dim3(6, 128), 256, 0, stream>>>(
        h3_all, W1T, nullptr, t1, ffn_b1, N_NODES, 768, 768);
    mm_k<2><<<dim3(6, 128), 256, 0, stream>>>(
        t1, W2T, nullptr, h4, ffn_b2, N_NODES, 768, 768);

    // ---- heads: logits GEMM (into dead h3 space) + softmax ----
    mm_k<0><<<dim3(1, 128), 256, 0, stream>>>(
        h4, WhT, Lg, nullptr, nullptr, N_NODES, 128, 768);
    hsm_k<<<(N_NODES + 3) / 4, 256, 0, stream>>>(
        Lg, mask, hl_b, int_b, act_b, (float*)d_out);
}